// Round 1
// baseline (367.646 us; speedup 1.0000x reference)
//
#include <hip/hip_runtime.h>
#include <math.h>

// Problem constants (from reference setup_inputs)
constexpr int B = 64, T = 2000, C = 100, K = 200, D = 2048;
constexpr float ALPHA = 0.0005f, BETA = 0.2f, LMBD = 1.0f, MARGIN = 100.0f, THRES = 0.5f;

constexpr int KSPLIT = 2;           // feat K split for more blocks
constexpr int KHALF  = K / KSPLIT;  // 100
constexpr int TT     = 10;          // sup time tiles
constexpr int TTILE  = T / TT;      // 200

// Workspace layout in floats
constexpr size_t WS_MEANPART = 0;                              // [2 tensors][KSPLIT][B][D]
constexpr size_t WS_NORMSQ   = (size_t)2 * KSPLIT * B * D;     // [2][B]
constexpr size_t WS_SUP_SSQ  = WS_NORMSQ + 2 * B;              // [B][C]
constexpr size_t WS_SUP_POS  = WS_SUP_SSQ + (size_t)B * C;     // [B][C]

// ---------------------------------------------------------------------------
// Kernel 1: per-(tensor, ksplit, b, d) partial sums over K of feat, float4.
// grid = 2 * KSPLIT * (B*D / (256*4)) = 2*2*128 = 512 blocks, 256 threads.
// ---------------------------------------------------------------------------
__global__ __launch_bounds__(256) void feat_sum_kernel(const float* __restrict__ feat_act,
                                                       const float* __restrict__ feat_bkg,
                                                       float* __restrict__ ws) {
    const int tensor = blockIdx.x >> 8;        // 0 or 1
    const int rem    = blockIdx.x & 255;
    const int split  = rem >> 7;               // 0 or 1
    const int blk    = rem & 127;

    const int vec = blk * 256 + threadIdx.x;   // 0 .. 32767 (B * D/4)
    const int b   = vec >> 9;                  // / (D/4 = 512)
    const int d4  = vec & 511;

    const float* __restrict__ feat = (tensor == 0) ? feat_act : feat_bkg;
    const float* p = feat + (size_t)b * K * D + (size_t)split * KHALF * D + (size_t)d4 * 4;

    float4 s = make_float4(0.f, 0.f, 0.f, 0.f);
#pragma unroll 4
    for (int k = 0; k < KHALF; ++k) {
        float4 v = *(const float4*)(p + (size_t)k * D);
        s.x += v.x; s.y += v.y; s.z += v.z; s.w += v.w;
    }

    float* dst = ws + WS_MEANPART +
                 ((size_t)((tensor * KSPLIT + split) * B + b)) * D + (size_t)d4 * 4;
    *(float4*)dst = s;
}

// ---------------------------------------------------------------------------
// Kernel 2: per-(tensor, b): combine K-halves, mean (/K), sum of squares over D.
// grid = 2*B = 128 blocks, 256 threads.
// ---------------------------------------------------------------------------
__global__ __launch_bounds__(256) void feat_normsq_kernel(float* __restrict__ ws) {
    const int tensor = blockIdx.x >> 6;
    const int b      = blockIdx.x & 63;
    const int tid    = threadIdx.x;

    const float* p0 = ws + WS_MEANPART + ((size_t)((tensor * KSPLIT + 0) * B + b)) * D;
    const float* p1 = ws + WS_MEANPART + ((size_t)((tensor * KSPLIT + 1) * B + b)) * D;

    float acc = 0.f;
    const float invK = 1.0f / (float)K;
    for (int d = tid; d < D; d += 256) {
        float m = (p0[d] + p1[d]) * invK;
        acc += m * m;
    }

    // block reduce (4 waves)
    __shared__ float sh[256];
    sh[tid] = acc;
    __syncthreads();
    for (int s = 128; s > 0; s >>= 1) {
        if (tid < s) sh[tid] += sh[tid + s];
        __syncthreads();
    }
    if (tid == 0) ws[WS_NORMSQ + (size_t)tensor * B + b] = sh[0];
}

// ---------------------------------------------------------------------------
// Kernel 3: loss_sup partials. grid = B*TT = 640 blocks, 256 threads.
// Thread (c = tid&127, tr = tid>>7) privately accumulates over its t-subset,
// LDS pair-reduce, then one global atomicAdd per (c, array).
// ---------------------------------------------------------------------------
__global__ __launch_bounds__(256) void sup_kernel(const float* __restrict__ gt,
                                                  const float* __restrict__ cas,
                                                  float* __restrict__ ssq_out,
                                                  float* __restrict__ pos_out) {
    const int b    = blockIdx.x / TT;
    const int tile = blockIdx.x % TT;
    const int t0   = tile * TTILE;

    const int tid = threadIdx.x;
    const int c   = tid & 127;
    const int tr  = tid >> 7;

    float ssq = 0.f, pos = 0.f;
    if (c < C) {
        for (int ti = tr; ti < TTILE; ti += 2) {
            size_t idx = ((size_t)b * T + (size_t)(t0 + ti)) * C + c;
            float g  = gt[idx];
            float ca = cas[idx];
            float pm = (g > THRES) ? 1.0f : 0.0f;
            float dd = ca - pm;
            ssq += dd * dd;
            pos += pm;
        }
    }

    __shared__ float sh_ssq[128];
    __shared__ float sh_pos[128];
    if (tr == 1) { sh_ssq[c] = ssq; sh_pos[c] = pos; }
    __syncthreads();
    if (tr == 0 && c < C) {
        atomicAdd(&ssq_out[(size_t)b * C + c], ssq + sh_ssq[c]);
        atomicAdd(&pos_out[(size_t)b * C + c], pos + sh_pos[c]);
    }
}

// ---------------------------------------------------------------------------
// Kernel 4: final scalar. 1 block, 256 threads, double accumulation.
// ---------------------------------------------------------------------------
__global__ __launch_bounds__(256) void final_kernel(const float* __restrict__ score_act,
                                                    const float* __restrict__ score_bkg,
                                                    const float* __restrict__ label,
                                                    const float* __restrict__ ws,
                                                    float* __restrict__ out) {
    const int tid = threadIdx.x;

    __shared__ float rowsum[B];
    if (tid < B) {
        float s = 0.f;
        const float* row = label + (size_t)tid * C;
        for (int c = 0; c < C; ++c) s += row[c];
        rowsum[tid] = s;
    }
    __syncthreads();

    const float* ssq_ws = ws + WS_SUP_SSQ;
    const float* pos_ws = ws + WS_SUP_POS;

    double cls = 0.0, be = 0.0, sup = 0.0, cnt = 0.0;
    const float invC = 1.0f / (float)C;
    for (int i = tid; i < B * C; i += 256) {
        int bb = i / C;
        float y = label[i] / rowsum[bb];

        float p   = score_act[i];
        float lp  = fmaxf(logf(p), -100.0f);
        float l1p = fmaxf(logf(1.0f - p), -100.0f);
        cls += (double)(y * lp + (1.0f - y) * l1p);

        float q   = score_bkg[i];
        float lq  = fmaxf(logf(q), -100.0f);
        float l1q = fmaxf(logf(1.0f - q), -100.0f);
        be += (double)(invC * lq + (1.0f - invC) * l1q);

        float pos = pos_ws[i];
        if (pos > 0.5f) {
            sup += (double)sqrtf(ssq_ws[i]);
            cnt += 1.0;
        }
    }

    double um = 0.0;
    if (tid < B) {
        float na = sqrtf(ws[WS_NORMSQ + tid]);
        float nb = sqrtf(ws[WS_NORMSQ + B + tid]);
        float la = fmaxf(MARGIN - na, 0.0f);
        float t  = la + nb;
        um = (double)t * (double)t;
    }

    __shared__ double sd[256];
    auto block_reduce = [&](double v) -> double {
        sd[tid] = v;
        __syncthreads();
        for (int s = 128; s > 0; s >>= 1) {
            if (tid < s) sd[tid] += sd[tid + s];
            __syncthreads();
        }
        double r = sd[0];
        __syncthreads();
        return r;
    };

    double cls_t = block_reduce(cls);
    double be_t  = block_reduce(be);
    double sup_t = block_reduce(sup);
    double cnt_t = block_reduce(cnt);
    double um_t  = block_reduce(um);

    if (tid == 0) {
        double loss_cls = -cls_t / (double)(B * C);
        double loss_be  = -be_t / (double)(B * C);
        double loss_um  = um_t / (double)B;
        double loss_sup = sup_t / cnt_t;
        out[0] = (float)(loss_cls + (double)ALPHA * loss_um +
                         (double)BETA * loss_be + (double)LMBD * loss_sup);
    }
}

extern "C" void kernel_launch(void* const* d_in, const int* in_sizes, int n_in,
                              void* d_out, int out_size, void* d_ws, size_t ws_size,
                              hipStream_t stream) {
    const float* score_act = (const float*)d_in[0];
    const float* score_bkg = (const float*)d_in[1];
    const float* feat_act  = (const float*)d_in[2];
    const float* feat_bkg  = (const float*)d_in[3];
    const float* label     = (const float*)d_in[4];
    const float* gt        = (const float*)d_in[5];
    const float* cas       = (const float*)d_in[6];

    float* ws  = (float*)d_ws;
    float* out = (float*)d_out;

    // zero only the atomic accumulation region (sup ssq + pos)
    hipMemsetAsync(ws + WS_SUP_SSQ, 0, 2 * (size_t)B * C * sizeof(float), stream);

    feat_sum_kernel<<<512, 256, 0, stream>>>(feat_act, feat_bkg, ws);
    feat_normsq_kernel<<<2 * B, 256, 0, stream>>>(ws);
    sup_kernel<<<B * TT, 256, 0, stream>>>(gt, cas, ws + WS_SUP_SSQ, ws + WS_SUP_POS);
    final_kernel<<<1, 256, 0, stream>>>(score_act, score_bkg, label, ws, out);
}

// Round 2
// 337.250 us; speedup vs baseline: 1.0901x; 1.0901x over previous
//
#include <hip/hip_runtime.h>
#include <math.h>

// Problem constants (from reference setup_inputs)
constexpr int B = 64, T = 2000, C = 100, K = 200, D = 2048;
constexpr float ALPHA = 0.0005f, BETA = 0.2f, LMBD = 1.0f, MARGIN = 100.0f, THRES = 0.5f;

constexpr int KSPLIT = 4;           // feat K split: grid = 2*4*128 = 1024 blocks
constexpr int KQ     = K / KSPLIT;  // 50 rows per split
constexpr int TT     = 20;          // sup time tiles: grid = 64*20 = 1280 blocks
constexpr int TTILE  = T / TT;      // 100 rows per tile

// Workspace layout in floats
constexpr size_t WS_MEANPART = 0;                              // [2][KSPLIT][B][D]
constexpr size_t WS_NORMSQ   = (size_t)2 * KSPLIT * B * D;     // [2][B]
constexpr size_t WS_SUP_SSQ  = WS_NORMSQ + 2 * B;              // [B][C]
constexpr size_t WS_SUP_POS  = WS_SUP_SSQ + (size_t)B * C;     // [B][C]

// ---------------------------------------------------------------------------
// Kernel 1: partial sums over K of feat, float4, 4-deep explicit ILP.
// grid = 2 * KSPLIT * 128 = 1024 blocks, 256 threads.
// ---------------------------------------------------------------------------
__global__ __launch_bounds__(256) void feat_sum_kernel(const float* __restrict__ feat_act,
                                                       const float* __restrict__ feat_bkg,
                                                       float* __restrict__ ws) {
    const int tensor = blockIdx.x >> 9;        // 0 or 1
    const int rem    = blockIdx.x & 511;
    const int split  = rem >> 7;               // 0..3
    const int blk    = rem & 127;

    const int vec = blk * 256 + threadIdx.x;   // 0 .. 32767 (B * D/4)
    const int b   = vec >> 9;                  // / (D/4 = 512)
    const int d4  = vec & 511;

    const float* __restrict__ feat = (tensor == 0) ? feat_act : feat_bkg;
    const float* p = feat + (size_t)b * K * D + (size_t)split * KQ * D + (size_t)d4 * 4;

    float4 a0 = make_float4(0.f, 0.f, 0.f, 0.f);
    float4 a1 = make_float4(0.f, 0.f, 0.f, 0.f);
    float4 a2 = make_float4(0.f, 0.f, 0.f, 0.f);
    float4 a3 = make_float4(0.f, 0.f, 0.f, 0.f);

    // 48 rows with 4 independent in-flight loads, then 2 remainder rows
    for (int k = 0; k < 48; k += 4) {
        float4 v0 = *(const float4*)(p + (size_t)(k + 0) * D);
        float4 v1 = *(const float4*)(p + (size_t)(k + 1) * D);
        float4 v2 = *(const float4*)(p + (size_t)(k + 2) * D);
        float4 v3 = *(const float4*)(p + (size_t)(k + 3) * D);
        a0.x += v0.x; a0.y += v0.y; a0.z += v0.z; a0.w += v0.w;
        a1.x += v1.x; a1.y += v1.y; a1.z += v1.z; a1.w += v1.w;
        a2.x += v2.x; a2.y += v2.y; a2.z += v2.z; a2.w += v2.w;
        a3.x += v3.x; a3.y += v3.y; a3.z += v3.z; a3.w += v3.w;
    }
    {
        float4 v0 = *(const float4*)(p + (size_t)48 * D);
        float4 v1 = *(const float4*)(p + (size_t)49 * D);
        a0.x += v0.x; a0.y += v0.y; a0.z += v0.z; a0.w += v0.w;
        a1.x += v1.x; a1.y += v1.y; a1.z += v1.z; a1.w += v1.w;
    }

    float4 s;
    s.x = (a0.x + a1.x) + (a2.x + a3.x);
    s.y = (a0.y + a1.y) + (a2.y + a3.y);
    s.z = (a0.z + a1.z) + (a2.z + a3.z);
    s.w = (a0.w + a1.w) + (a2.w + a3.w);

    float* dst = ws + WS_MEANPART +
                 ((size_t)((tensor * KSPLIT + split) * B + b)) * D + (size_t)d4 * 4;
    *(float4*)dst = s;
}

// ---------------------------------------------------------------------------
// Kernel 2: per-(tensor, b): combine KSPLIT partials, mean (/K), sum sq over D.
// grid = 2*B = 128 blocks, 256 threads.
// ---------------------------------------------------------------------------
__global__ __launch_bounds__(256) void feat_normsq_kernel(float* __restrict__ ws) {
    const int tensor = blockIdx.x >> 6;
    const int b      = blockIdx.x & 63;
    const int tid    = threadIdx.x;

    const float* p0 = ws + WS_MEANPART + ((size_t)((tensor * KSPLIT + 0) * B + b)) * D;
    const float* p1 = ws + WS_MEANPART + ((size_t)((tensor * KSPLIT + 1) * B + b)) * D;
    const float* p2 = ws + WS_MEANPART + ((size_t)((tensor * KSPLIT + 2) * B + b)) * D;
    const float* p3 = ws + WS_MEANPART + ((size_t)((tensor * KSPLIT + 3) * B + b)) * D;

    float acc = 0.f;
    const float invK = 1.0f / (float)K;
    for (int d = tid; d < D; d += 256) {
        float m = ((p0[d] + p1[d]) + (p2[d] + p3[d])) * invK;
        acc += m * m;
    }

    __shared__ float sh[256];
    sh[tid] = acc;
    __syncthreads();
    for (int s = 128; s > 0; s >>= 1) {
        if (tid < s) sh[tid] += sh[tid + s];
        __syncthreads();
    }
    if (tid == 0) ws[WS_NORMSQ + (size_t)tensor * B + b] = sh[0];
}

// ---------------------------------------------------------------------------
// Kernel 3: loss_sup partials, float4 fully-contiguous loads.
// grid = B*TT = 1280 blocks, 256 threads (250 active).
// thread: c4 = tid%25 (4 classes), t_row = tid/25 (0..9); the 250 active
// threads read 4000 contiguous bytes per step (rows are 400 B, contiguous).
// ---------------------------------------------------------------------------
__global__ __launch_bounds__(256) void sup_kernel(const float* __restrict__ gt,
                                                  const float* __restrict__ cas,
                                                  float* __restrict__ ssq_out,
                                                  float* __restrict__ pos_out) {
    const int b    = blockIdx.x / TT;
    const int tile = blockIdx.x % TT;
    const int t0   = tile * TTILE;

    const int tid = threadIdx.x;
    const int c4  = tid % 25;      // float4 index within a row
    const int tl  = tid / 25;      // 0..9 (tid>=250 -> tl==10, inactive)

    __shared__ float sh_ssq[C];
    __shared__ float sh_pos[C];
    if (tid < C) { sh_ssq[tid] = 0.f; sh_pos[tid] = 0.f; }
    __syncthreads();

    if (tl < 10) {
        const size_t base = ((size_t)b * T + (size_t)t0) * C + (size_t)c4 * 4;

        float4 ssq = make_float4(0.f, 0.f, 0.f, 0.f);
        float4 pos = make_float4(0.f, 0.f, 0.f, 0.f);

        // TTILE=100 rows, 10 per pass, unroll 2 -> 4 loads in flight
        for (int i = 0; i < 10; i += 2) {
            size_t off0 = base + (size_t)(tl + 10 * (i + 0)) * C;
            size_t off1 = base + (size_t)(tl + 10 * (i + 1)) * C;
            float4 g0 = *(const float4*)(gt + off0);
            float4 q0 = *(const float4*)(cas + off0);
            float4 g1 = *(const float4*)(gt + off1);
            float4 q1 = *(const float4*)(cas + off1);

            float pm, dd;
            pm = (g0.x > THRES) ? 1.f : 0.f; dd = q0.x - pm; ssq.x += dd * dd; pos.x += pm;
            pm = (g0.y > THRES) ? 1.f : 0.f; dd = q0.y - pm; ssq.y += dd * dd; pos.y += pm;
            pm = (g0.z > THRES) ? 1.f : 0.f; dd = q0.z - pm; ssq.z += dd * dd; pos.z += pm;
            pm = (g0.w > THRES) ? 1.f : 0.f; dd = q0.w - pm; ssq.w += dd * dd; pos.w += pm;
            pm = (g1.x > THRES) ? 1.f : 0.f; dd = q1.x - pm; ssq.x += dd * dd; pos.x += pm;
            pm = (g1.y > THRES) ? 1.f : 0.f; dd = q1.y - pm; ssq.y += dd * dd; pos.y += pm;
            pm = (g1.z > THRES) ? 1.f : 0.f; dd = q1.z - pm; ssq.z += dd * dd; pos.z += pm;
            pm = (g1.w > THRES) ? 1.f : 0.f; dd = q1.w - pm; ssq.w += dd * dd; pos.w += pm;
        }

        const int c = c4 * 4;
        atomicAdd(&sh_ssq[c + 0], ssq.x);
        atomicAdd(&sh_ssq[c + 1], ssq.y);
        atomicAdd(&sh_ssq[c + 2], ssq.z);
        atomicAdd(&sh_ssq[c + 3], ssq.w);
        atomicAdd(&sh_pos[c + 0], pos.x);
        atomicAdd(&sh_pos[c + 1], pos.y);
        atomicAdd(&sh_pos[c + 2], pos.z);
        atomicAdd(&sh_pos[c + 3], pos.w);
    }
    __syncthreads();

    if (tid < C) {
        atomicAdd(&ssq_out[(size_t)b * C + tid], sh_ssq[tid]);
        atomicAdd(&pos_out[(size_t)b * C + tid], sh_pos[tid]);
    }
}

// ---------------------------------------------------------------------------
// Kernel 4: final scalar. 1 block, 256 threads, double accumulation.
// ---------------------------------------------------------------------------
__global__ __launch_bounds__(256) void final_kernel(const float* __restrict__ score_act,
                                                    const float* __restrict__ score_bkg,
                                                    const float* __restrict__ label,
                                                    const float* __restrict__ ws,
                                                    float* __restrict__ out) {
    const int tid = threadIdx.x;

    __shared__ float rowsum[B];
    if (tid < B) {
        float s = 0.f;
        const float* row = label + (size_t)tid * C;
        for (int c = 0; c < C; ++c) s += row[c];
        rowsum[tid] = s;
    }
    __syncthreads();

    const float* ssq_ws = ws + WS_SUP_SSQ;
    const float* pos_ws = ws + WS_SUP_POS;

    double cls = 0.0, be = 0.0, sup = 0.0, cnt = 0.0;
    const float invC = 1.0f / (float)C;
    for (int i = tid; i < B * C; i += 256) {
        int bb = i / C;
        float y = label[i] / rowsum[bb];

        float p   = score_act[i];
        float lp  = fmaxf(logf(p), -100.0f);
        float l1p = fmaxf(logf(1.0f - p), -100.0f);
        cls += (double)(y * lp + (1.0f - y) * l1p);

        float q   = score_bkg[i];
        float lq  = fmaxf(logf(q), -100.0f);
        float l1q = fmaxf(logf(1.0f - q), -100.0f);
        be += (double)(invC * lq + (1.0f - invC) * l1q);

        float pos = pos_ws[i];
        if (pos > 0.5f) {
            sup += (double)sqrtf(ssq_ws[i]);
            cnt += 1.0;
        }
    }

    double um = 0.0;
    if (tid < B) {
        float na = sqrtf(ws[WS_NORMSQ + tid]);
        float nb = sqrtf(ws[WS_NORMSQ + B + tid]);
        float la = fmaxf(MARGIN - na, 0.0f);
        float t  = la + nb;
        um = (double)t * (double)t;
    }

    __shared__ double sd[256];
    auto block_reduce = [&](double v) -> double {
        sd[tid] = v;
        __syncthreads();
        for (int s = 128; s > 0; s >>= 1) {
            if (tid < s) sd[tid] += sd[tid + s];
            __syncthreads();
        }
        double r = sd[0];
        __syncthreads();
        return r;
    };

    double cls_t = block_reduce(cls);
    double be_t  = block_reduce(be);
    double sup_t = block_reduce(sup);
    double cnt_t = block_reduce(cnt);
    double um_t  = block_reduce(um);

    if (tid == 0) {
        double loss_cls = -cls_t / (double)(B * C);
        double loss_be  = -be_t / (double)(B * C);
        double loss_um  = um_t / (double)B;
        double loss_sup = sup_t / cnt_t;
        out[0] = (float)(loss_cls + (double)ALPHA * loss_um +
                         (double)BETA * loss_be + (double)LMBD * loss_sup);
    }
}

extern "C" void kernel_launch(void* const* d_in, const int* in_sizes, int n_in,
                              void* d_out, int out_size, void* d_ws, size_t ws_size,
                              hipStream_t stream) {
    const float* score_act = (const float*)d_in[0];
    const float* score_bkg = (const float*)d_in[1];
    const float* feat_act  = (const float*)d_in[2];
    const float* feat_bkg  = (const float*)d_in[3];
    const float* label     = (const float*)d_in[4];
    const float* gt        = (const float*)d_in[5];
    const float* cas       = (const float*)d_in[6];

    float* ws  = (float*)d_ws;
    float* out = (float*)d_out;

    // zero only the atomic accumulation region (sup ssq + pos)
    hipMemsetAsync(ws + WS_SUP_SSQ, 0, 2 * (size_t)B * C * sizeof(float), stream);

    feat_sum_kernel<<<2 * KSPLIT * 128, 256, 0, stream>>>(feat_act, feat_bkg, ws);
    feat_normsq_kernel<<<2 * B, 256, 0, stream>>>(ws);
    sup_kernel<<<B * TT, 256, 0, stream>>>(gt, cas, ws + WS_SUP_SSQ, ws + WS_SUP_POS);
    final_kernel<<<1, 256, 0, stream>>>(score_act, score_bkg, label, ws, out);
}